// Round 4
// baseline (132.723 us; speedup 1.0000x reference)
//
#include <hip/hip_runtime.h>

// Z: (2049, 8193) fp32, alpha: (1,) fp32.
// out = Z, except last row: out[2048, j] = Z[2048,j] + (alpha/N) * sum_{c<D} v[c]*(Z[c+D,j]-Z[c,j])
// where v[c] = sum_{j<N} Z[2048, j] * Z[c, j]   (j < N only: M kills column N)
//
// 2-kernel structure, minimum traffic:
//  K1 copy_dot: flat 16B-aligned copy Z->out (134 MB, the HBM floor) fused with the
//     row-dot. Each flat block spans <=2 rows; it stores its two row-partials to
//     slot[2b], slot[2b+1] unconditionally -> no atomics, no zero pass, no prep.
//     v[r] = slot[2r+1] + slot[2r+2] by construction.
//  K2 corr: block b < 256 owns a 128-byte j-window of the last row; loops all 1024 c's
//     (Z is L3-resident after K1), reduces in-wave + LDS, writes the final last row
//     directly. Block 256 handles the tail column j=8192. No partials, no finalize.

#define D   1024
#define N   8192
#define DD  2049
#define N1  8193
#define TOTAL_DW 16787457u   // 2049*8193
#define TOTAL_Q  4196864u    // full aligned quads; +1 tail dword

typedef float f32x4a __attribute__((ext_vector_type(4), aligned(16)));
typedef float f32x4u __attribute__((ext_vector_type(4), aligned(4)));  // 4B-aligned ok for global dwordx4

// ---------------- K1: flat aligned copy + fused dot partials ----------------
// grid = 2050 x 512; block covers 2048 quads (8192 dwords) -> rows rA, rA+1 only.
__global__ void __launch_bounds__(512) copy_dot(const float* __restrict__ Z,
                                                float* __restrict__ out,
                                                float* __restrict__ slot) {
    const uint b = blockIdx.x, t = threadIdx.x;
    const float* __restrict__ u = Z + (size_t)(DD - 1) * N1;   // last row, 16B-aligned
    const uint rA = (b * 8192u) / 8193u;        // row of block's first dword (= b-1 for b>=1)
    const bool dotBlk = (rA < (uint)D);
    float accA = 0.f, accB = 0.f;

    #pragma unroll
    for (int it = 0; it < 4; ++it) {
        const uint q = b * 2048u + t + it * 512u;
        if (q >= TOTAL_Q) continue;             // only last block clips
        const uint g0 = q * 4u;                 // flat dword index, 16B-aligned
        f32x4a a = *(const f32x4a*)(Z + g0);
        __builtin_nontemporal_store(a, (f32x4a*)(out + g0));
        if (dotBlk) {
            const uint r = g0 / 8193u;          // magic-mul division
            if (r < (uint)D) {
                const uint j0 = g0 - r * 8193u;
                if (j0 + 3u < 8192u) {          // quad fully inside dot range of row r
                    f32x4u s = *(const f32x4u*)(u + j0);   // HW handles 4B alignment
                    const float dsum = a.x * s.x + a.y * s.y + a.z * s.z + a.w * s.w;
                    if (r == rA) accA += dsum; else accB += dsum;
                } else {                        // boundary quad (j0 >= 8189): scalar fixup
                    const float ae[4] = {a.x, a.y, a.z, a.w};
                    #pragma unroll
                    for (int e = 0; e < 4; ++e) {
                        uint rr = r, j = j0 + (uint)e;
                        if (j > (uint)N) { rr = r + 1u; j -= (uint)N1; }
                        if (rr < (uint)D && j < (uint)N) {
                            const float dv = ae[e] * u[j];
                            if (rr == rA) accA += dv; else accB += dv;
                        }
                    }
                }
            }
        }
    }
    if (b == 0 && t == 0) out[TOTAL_DW - 1u] = Z[TOTAL_DW - 1u];  // tail dword [2048][8192]

    if (dotBlk) {
        #pragma unroll
        for (int off = 32; off > 0; off >>= 1) {
            accA += __shfl_down(accA, off, 64);
            accB += __shfl_down(accB, off, 64);
        }
        __shared__ float smA[8], smB[8];
        if ((t & 63u) == 0u) { smA[t >> 6] = accA; smB[t >> 6] = accB; }
        __syncthreads();
        if (t == 0) {
            float sA = 0.f, sB = 0.f;
            #pragma unroll
            for (int w = 0; w < 8; ++w) { sA += smA[w]; sB += smB[w]; }
            if (b == 0) { slot[0] = 0.f; slot[1] = sA; }   // block 0: its only row (0) is a "B" row
            else        { slot[2 * b] = sA; slot[2 * b + 1] = sB; }
        }
    }
}

// ---------------- K2: correction + final last-row write ----------------
// grid = 257 x 512. Blocks 0..255: j-window of 32 dwords (128B). Thread t = jq(8) x cg(64);
// cg covers 16 c's. Rows read as 8-lane contiguous 128B segments (coalesced). Block 256:
// tail column j = 8192, scalar.
__global__ void __launch_bounds__(512) corr(const float* __restrict__ Z,
                                            const float* __restrict__ slot,
                                            const float* __restrict__ alpha,
                                            float* __restrict__ out) {
    __shared__ float vsm[1024];
    __shared__ float red[8][8][4];   // [wave][jq][component]
    const int t = threadIdx.x;
    const int b = blockIdx.x;

    // v[c] = slot[2c+1] + slot[2c+2]
    #pragma unroll
    for (int c = t; c < 1024; c += 512)
        vsm[c] = slot[2 * c + 1] + slot[2 * c + 2];
    __syncthreads();

    const float scale = alpha[0] / (float)N;
    const float* __restrict__ zl = Z   + (size_t)(DD - 1) * N1;   // 16B-aligned
    float*       __restrict__ o  = out + (size_t)(DD - 1) * N1;

    if (b < 256) {
        const int jq = t & 7;            // j-quad within the 128B window
        const int cg = t >> 3;           // c-group (16 c's)
        const int j0 = b * 32 + jq * 4;
        float ax = 0.f, ay = 0.f, az = 0.f, aw = 0.f;
        #pragma unroll 8
        for (int m = 0; m < 16; ++m) {
            const int c = cg * 16 + m;
            const float vc = vsm[c];
            f32x4u zp = *(const f32x4u*)(Z + (size_t)(c + D) * N1 + j0);
            f32x4u zm = *(const f32x4u*)(Z + (size_t)c * N1 + j0);
            ax += vc * (zp.x - zm.x);
            ay += vc * (zp.y - zm.y);
            az += vc * (zp.z - zm.z);
            aw += vc * (zp.w - zm.w);
        }
        // in-wave: combine the 8 cg's that share this wave (lane = jq + 8*cg_local)
        #pragma unroll
        for (int off = 32; off >= 8; off >>= 1) {
            ax += __shfl_down(ax, off, 64);
            ay += __shfl_down(ay, off, 64);
            az += __shfl_down(az, off, 64);
            aw += __shfl_down(aw, off, 64);
        }
        if ((t & 63) < 8) {
            const int w = t >> 6;
            red[w][jq][0] = ax; red[w][jq][1] = ay; red[w][jq][2] = az; red[w][jq][3] = aw;
        }
        __syncthreads();
        if (t < 8) {   // one thread per jq: sum 8 waves, write 16B of the last row
            float sx = 0.f, sy = 0.f, sz = 0.f, sw = 0.f;
            #pragma unroll
            for (int w = 0; w < 8; ++w) {
                sx += red[w][t][0]; sy += red[w][t][1];
                sz += red[w][t][2]; sw += red[w][t][3];
            }
            const int jb = b * 32 + t * 4;
            f32x4a z = *(const f32x4a*)(zl + jb);
            f32x4a r = {z.x + scale * sx, z.y + scale * sy,
                        z.z + scale * sz, z.w + scale * sw};
            *(f32x4a*)(o + jb) = r;
        }
    } else {
        // tail column j = 8192: 512 threads x 2 c's each
        float s = 0.f;
        #pragma unroll
        for (int k = 0; k < 2; ++k) {
            const int c = t * 2 + k;
            s += vsm[c] * (Z[(size_t)(c + D) * N1 + N] - Z[(size_t)c * N1 + N]);
        }
        #pragma unroll
        for (int off = 32; off > 0; off >>= 1)
            s += __shfl_down(s, off, 64);
        __shared__ float sm[8];
        if ((t & 63) == 0) sm[t >> 6] = s;
        __syncthreads();
        if (t == 0) {
            float tot = 0.f;
            #pragma unroll
            for (int w = 0; w < 8; ++w) tot += sm[w];
            o[N] = zl[N] + scale * tot;
        }
    }
}

extern "C" void kernel_launch(void* const* d_in, const int* in_sizes, int n_in,
                              void* d_out, int out_size, void* d_ws, size_t ws_size,
                              hipStream_t stream) {
    const float* Z     = (const float*)d_in[0];
    const float* alpha = (const float*)d_in[1];
    float* out  = (float*)d_out;
    float* slot = (float*)d_ws;   // 2050 floats (~8.2 KB)

    copy_dot<<<2050, 512, 0, stream>>>(Z, out, slot);
    corr    <<<257, 512, 0, stream>>>(Z, slot, alpha, out);
}

// Round 6
// 126.279 us; speedup vs baseline: 1.0510x; 1.0510x over previous
//
#include <hip/hip_runtime.h>

// Z: (2049, 8193) fp32, alpha: (1,) fp32.
// out = Z, except last row: out[2048, j] += (alpha/N) * sum_{c<D} v[c]*(Z[c+D,j]-Z[c,j])
// where v[c] = sum_{j<N} Z[2048, j] * Z[c, j]   (j < N only: M kills column N)
//
// Structure = round-0 best (129.8 us) with K2 retuned for occupancy:
//  K1: per-row copy + fused dot (2049 blocks x 512). Copies ALL rows (incl row 2048,
//      which serves as the atomic base for K2).
//  K2: correction, grid (64 j-windows x 32 c-splits) = 2048 blocks x 256 thr
//      = 8 blocks/CU (32 waves/CU, max occupancy) vs round-0's 2/CU.
//      Per-block shuffle+LDS reduce over its 32 c's, then 4 atomicAdds/thread-slot
//      (262K atomics, 32-way contention - measured harmless in round 0).

#define D   1024
#define N   8192
#define DD  2049
#define N1  8193

typedef float f32x4u __attribute__((ext_vector_type(4), aligned(4)));  // rows start at phase (r*8193)%4

// ---------------- Kernel 1: row-parallel copy + fused dot ----------------
// grid = 2049 blocks (one per row) x 512 threads. Each thread: 4 quads (16 floats).
// Rows r < 1024 also accumulate v[r] = dot(row, u) over j=0..8191 from the SAME registers.
__global__ void __launch_bounds__(512) copy_dot_rows(const float* __restrict__ Z,
                                                     float* __restrict__ out,
                                                     float* __restrict__ v) {
    const int r = blockIdx.x;
    const int t = threadIdx.x;
    const float* __restrict__ row  = Z   + (long)r * N1;
    float*       __restrict__ orow = out + (long)r * N1;
    const float* __restrict__ u    = Z   + (long)(DD - 1) * N1;   // 16B-aligned (2048*8193 % 4 == 0)

    if (r < D) {
        float acc = 0.f;
        #pragma unroll
        for (int it = 0; it < 4; ++it) {
            const int q = t + it * 512;          // quad 0..2047 -> j = 4q..4q+3 (j<8192)
            f32x4u a = *(const f32x4u*)(row + 4 * q);
            f32x4u b = *(const f32x4u*)(u   + 4 * q);
            __builtin_nontemporal_store(a, (f32x4u*)(orow + 4 * q));
            acc += a.x * b.x + a.y * b.y + a.z * b.z + a.w * b.w;
        }
        // reduce 512 threads: wave butterfly then 8-slot LDS
        #pragma unroll
        for (int off = 32; off > 0; off >>= 1)
            acc += __shfl_down(acc, off, 64);
        __shared__ float smem[8];
        if ((t & 63) == 0) smem[t >> 6] = acc;
        __syncthreads();
        if (t == 0) {
            float s = 0.f;
            #pragma unroll
            for (int w = 0; w < 8; ++w) s += smem[w];
            v[r] = s;
        }
    } else {
        #pragma unroll
        for (int it = 0; it < 4; ++it) {
            const int q = t + it * 512;
            f32x4u a = *(const f32x4u*)(row + 4 * q);
            __builtin_nontemporal_store(a, (f32x4u*)(orow + 4 * q));
        }
    }
    if (t == 511) orow[N] = row[N];              // tail element j = 8192 of each row
}

// ---------------- Kernel 2: last-row correction, high-occupancy ----------------
// grid = (64, 32) x 256: bx = 128-dword j-window, by = 32-c split.
// Thread t: jq = t&31 (quad in window), cg = t>>5 (8 groups of 4 c's).
// 8 dwordx4 loads/thread; cg-reduce via shfl(32) + LDS; 4 atomicAdds per jq-slot.
__global__ void __launch_bounds__(256) corr_kernel(const float* __restrict__ Z,
                                                   const float* __restrict__ v,
                                                   const float* __restrict__ alpha,
                                                   float* __restrict__ out) {
    const int t  = threadIdx.x;
    const int jq = t & 31;
    const int cg = t >> 5;                         // 0..7
    const int j0 = blockIdx.x * 128 + jq * 4;
    const int cbase = blockIdx.y * 32 + cg * 4;
    const float scale = alpha[0] / (float)N;

    float ax = 0.f, ay = 0.f, az = 0.f, aw = 0.f;
    #pragma unroll
    for (int m = 0; m < 4; ++m) {
        const int c = cbase + m;
        const float vc = v[c];
        f32x4u zp = *(const f32x4u*)(Z + (size_t)(c + D) * N1 + j0);
        f32x4u zm = *(const f32x4u*)(Z + (size_t)c * N1 + j0);
        ax += vc * (zp.x - zm.x);
        ay += vc * (zp.y - zm.y);
        az += vc * (zp.z - zm.z);
        aw += vc * (zp.w - zm.w);
    }
    // combine cg pairs within each wave: lane l (<32) += lane l+32
    ax += __shfl_down(ax, 32, 64);
    ay += __shfl_down(ay, 32, 64);
    az += __shfl_down(az, 32, 64);
    aw += __shfl_down(aw, 32, 64);
    __shared__ float red[4][32][4];                // [wave][jq][component]
    const int w = t >> 6;                          // 0..3
    if ((t & 63) < 32) {
        red[w][t & 31][0] = ax; red[w][t & 31][1] = ay;
        red[w][t & 31][2] = az; red[w][t & 31][3] = aw;
    }
    __syncthreads();
    if (t < 32) {                                  // one thread per jq: sum 4 waves (= 8 cg's)
        float sx = 0.f, sy = 0.f, sz = 0.f, sw = 0.f;
        #pragma unroll
        for (int ww = 0; ww < 4; ++ww) {
            sx += red[ww][t][0]; sy += red[ww][t][1];
            sz += red[ww][t][2]; sw += red[ww][t][3];
        }
        float* o = out + (size_t)(DD - 1) * N1 + blockIdx.x * 128 + t * 4;
        atomicAdd(o + 0, scale * sx);
        atomicAdd(o + 1, scale * sy);
        atomicAdd(o + 2, scale * sz);
        atomicAdd(o + 3, scale * sw);
    }
    // tail column j = 8192 (each c-split adds its 32-c share)
    if (blockIdx.x == 0 && t == 0) {
        float lt = 0.f;
        #pragma unroll
        for (int m = 0; m < 32; ++m) {
            const int c = blockIdx.y * 32 + m;
            lt += v[c] * (Z[(size_t)(c + D) * N1 + N] - Z[(size_t)c * N1 + N]);
        }
        atomicAdd(out + (size_t)(DD - 1) * N1 + N, scale * lt);
    }
}

extern "C" void kernel_launch(void* const* d_in, const int* in_sizes, int n_in,
                              void* d_out, int out_size, void* d_ws, size_t ws_size,
                              hipStream_t stream) {
    const float* Z     = (const float*)d_in[0];
    const float* alpha = (const float*)d_in[1];
    float* out = (float*)d_out;
    float* v   = (float*)d_ws;   // D floats = 4 KB scratch

    copy_dot_rows<<<DD, 512, 0, stream>>>(Z, out, v);
    corr_kernel<<<dim3(64, 32), 256, 0, stream>>>(Z, v, alpha, out);
}